// Round 2
// baseline (113.459 us; speedup 1.0000x reference)
//
#include <hip/hip_runtime.h>
#include <hip/hip_cooperative_groups.h>
#include <math.h>

namespace cg = cooperative_groups;

#define N_ROWS   8192
#define DIM      128
#define NCLASS   100
#define EPS      1e-8f

#define NBLOCK   256
#define NTHREAD  256
#define NWAVES   (NBLOCK * NTHREAD / 64)          // 1024
#define ROWS_PER_WAVE (N_ROWS / NWAVES)           // 8

// ws layout (floats): C[NCLASS*DIM], then loss accumulator
#define ACC_OFF (NCLASS * DIM)

__global__ void __launch_bounds__(NTHREAD, 1)
ntx_fused(const float* __restrict__ z,
          const int*   __restrict__ labels,
          float* __restrict__ C,
          float* __restrict__ acc,
          float* __restrict__ out)
{
    cg::grid_group grid = cg::this_grid();
    const int tid  = blockIdx.x * blockDim.x + threadIdx.x;
    const int lane = threadIdx.x & 63;
    const int wave = tid >> 6;                    // 0..1023

    // ---- Phase A: zero C and the loss accumulator ----
    for (int i = tid; i < NCLASS * DIM; i += NBLOCK * NTHREAD) C[i] = 0.0f;
    if (tid == 0) *acc = 0.0f;
    grid.sync();

    // ---- Phase B: per-class sums of normalized rows ----
    // lane owns dims {2*lane, 2*lane+1} via one float2 load per row.
    for (int r = 0; r < ROWS_PER_WAVE; ++r) {
        int row = wave * ROWS_PER_WAVE + r;
        float2 v = ((const float2*)(z + (size_t)row * DIM))[lane];
        float ss = v.x * v.x + v.y * v.y;
        #pragma unroll
        for (int off = 1; off < 64; off <<= 1) ss += __shfl_xor(ss, off);
        float inv = 1.0f / fmaxf(sqrtf(ss), EPS);
        int lbl = labels[row];
        atomicAdd(&C[lbl * DIM + 2 * lane],     v.x * inv);
        atomicAdd(&C[lbl * DIM + 2 * lane + 1], v.y * inv);
    }
    grid.sync();

    // ---- Phase C: per-block total-sum vector S in LDS ----
    __shared__ float Sl[DIM];
    if (threadIdx.x < DIM) {
        float s = 0.0f;
        for (int c = 0; c < NCLASS; ++c) s += C[c * DIM + threadIdx.x];
        Sl[threadIdx.x] = s;
    }
    __syncthreads();

    // ---- Phase D: per-row loss ----
    float lacc = 0.0f;
    for (int r = 0; r < ROWS_PER_WAVE; ++r) {
        int row = wave * ROWS_PER_WAVE + r;
        float2 v  = ((const float2*)(z + (size_t)row * DIM))[lane];
        int lbl   = labels[row];
        float2 c2 = ((const float2*)(C + lbl * DIM))[lane];
        float sx = Sl[2 * lane], sy = Sl[2 * lane + 1];

        float ss = v.x * v.x + v.y * v.y;
        float dc = v.x * c2.x + v.y * c2.y;
        float dt = v.x * sx   + v.y * sy;
        #pragma unroll
        for (int off = 1; off < 64; off <<= 1) {
            ss += __shfl_xor(ss, off);
            dc += __shfl_xor(dc, off);
            dt += __shfl_xor(dt, off);
        }
        float inv  = 1.0f / fmaxf(sqrtf(ss), EPS);
        float self = ss * inv * inv;              // zn_i . zn_i (== 1)
        float pos  = dc * inv - self;             // 1/TEMP cancels in the ratio
        float tot  = dt * inv;
        lacc += -logf(pos / tot);
    }
    if (lane == 0) atomicAdd(acc, lacc);          // 1024 adds
    grid.sync();

    // ---- Phase E: final mean ----
    if (tid == 0) out[0] = *acc * (1.0f / (float)N_ROWS);
}

extern "C" void kernel_launch(void* const* d_in, const int* in_sizes, int n_in,
                              void* d_out, int out_size, void* d_ws, size_t ws_size,
                              hipStream_t stream) {
    const float* z      = (const float*)d_in[0];
    const int*   labels = (const int*)d_in[1];
    float* out = (float*)d_out;
    float* ws  = (float*)d_ws;
    float* C   = ws;
    float* acc = ws + ACC_OFF;

    (void)in_sizes; (void)n_in; (void)out_size; (void)ws_size;

    void* args[] = { (void*)&z, (void*)&labels, (void*)&C, (void*)&acc, (void*)&out };
    hipLaunchCooperativeKernel((void*)ntx_fused, dim3(NBLOCK), dim3(NTHREAD),
                               args, 0, stream);
}

// Round 3
// 74.507 us; speedup vs baseline: 1.5228x; 1.5228x over previous
//
#include <hip/hip_runtime.h>
#include <math.h>

#define N_ROWS   8192
#define DIM      128
#define NCLASS   100
#define EPS      1e-8f

#define CD       (NCLASS * DIM)      // 12800 floats per class-sum matrix
#define MAXP     64                  // max partial copies (K1 blocks)

// ws layout (floats):
//   [0 .. P*CD)          partial class sums (one private copy per K1 block)
//   [MAXP*CD .. +CD)     C   (reduced class sums)
//   [MAXP*CD+CD .. +128) S   (total sum vector)
#define C_OFF  (MAXP * CD)
#define S_OFF  (MAXP * CD + CD)

// K1: per-block LDS class-sum accumulation -> private partial in ws.
// Block 0 also zeroes S and out.
__global__ void __launch_bounds__(256)
ntx_partials(const float* __restrict__ z,
             const int*   __restrict__ labels,
             float* __restrict__ partials,
             float* __restrict__ S,
             float* __restrict__ out,
             int nblocks)
{
    __shared__ float Cl[CD];
    for (int i = threadIdx.x; i < CD; i += 256) Cl[i] = 0.0f;
    if (blockIdx.x == 0) {
        if (threadIdx.x < DIM) S[threadIdx.x] = 0.0f;
        if (threadIdx.x == DIM) out[0] = 0.0f;
    }
    __syncthreads();

    const int lane    = threadIdx.x & 63;
    const int wg      = (blockIdx.x * 256 + threadIdx.x) >> 6;  // global wave id
    const int totwave = nblocks * 4;

    for (int row = wg; row < N_ROWS; row += totwave) {
        float2 v = ((const float2*)(z + (size_t)row * DIM))[lane];
        float ss = v.x * v.x + v.y * v.y;
        #pragma unroll
        for (int off = 1; off < 64; off <<= 1) ss += __shfl_xor(ss, off);
        float inv = 1.0f / fmaxf(sqrtf(ss), EPS);
        int lbl = labels[row];
        atomicAdd(&Cl[lbl * DIM + 2 * lane],     v.x * inv);
        atomicAdd(&Cl[lbl * DIM + 2 * lane + 1], v.y * inv);
    }
    __syncthreads();

    float* mine = partials + (size_t)blockIdx.x * CD;
    for (int i = threadIdx.x; i < CD; i += 256) mine[i] = Cl[i];
}

// K2: C[i] = sum_p partials[p][i];  S[d] += column sums (atomic, 100-way).
__global__ void __launch_bounds__(256)
ntx_reduce(const float* __restrict__ partials,
           float* __restrict__ C,
           float* __restrict__ S,
           int P)
{
    int i = blockIdx.x * 256 + threadIdx.x;
    if (i >= CD) return;
    float s = 0.0f;
    for (int p = 0; p < P; ++p) s += partials[(size_t)p * CD + i];
    C[i] = s;
    atomicAdd(&S[i & (DIM - 1)], s);
}

// K3: per-row loss, mean accumulated directly into out.
__global__ void __launch_bounds__(256)
ntx_loss(const float* __restrict__ z,
         const int*   __restrict__ labels,
         const float* __restrict__ C,
         const float* __restrict__ S,
         float* __restrict__ out)
{
    __shared__ float Sl[DIM];
    if (threadIdx.x < DIM) Sl[threadIdx.x] = S[threadIdx.x];
    __syncthreads();

    const int lane    = threadIdx.x & 63;
    const int wg      = (blockIdx.x * 256 + threadIdx.x) >> 6;
    const int totwave = gridDim.x * 4;

    float lacc = 0.0f;
    for (int row = wg; row < N_ROWS; row += totwave) {
        float2 v  = ((const float2*)(z + (size_t)row * DIM))[lane];
        int lbl   = labels[row];
        float2 c2 = ((const float2*)(C + (size_t)lbl * DIM))[lane];
        float sx  = Sl[2 * lane], sy = Sl[2 * lane + 1];

        float ss = v.x * v.x + v.y * v.y;
        float dc = v.x * c2.x + v.y * c2.y;
        float dt = v.x * sx   + v.y * sy;
        #pragma unroll
        for (int off = 1; off < 64; off <<= 1) {
            ss += __shfl_xor(ss, off);
            dc += __shfl_xor(dc, off);
            dt += __shfl_xor(dt, off);
        }
        float inv  = 1.0f / fmaxf(sqrtf(ss), EPS);
        float self = ss * inv * inv;          // zn_i . zn_i (diagonal term)
        float pos  = dc * inv - self;         // 1/TEMP cancels in pos/tot
        float tot  = dt * inv;
        lacc += -logf(pos / tot);
    }
    if (lane == 0) atomicAdd(out, lacc * (1.0f / (float)N_ROWS));
}

extern "C" void kernel_launch(void* const* d_in, const int* in_sizes, int n_in,
                              void* d_out, int out_size, void* d_ws, size_t ws_size,
                              hipStream_t stream) {
    const float* z      = (const float*)d_in[0];
    const int*   labels = (const int*)d_in[1];
    float* out = (float*)d_out;
    float* ws  = (float*)d_ws;

    (void)in_sizes; (void)n_in; (void)out_size;

    // choose partial count that fits ws (profile showed ws ~256 MB; P=64 needs 3.3 MB)
    int P = MAXP;
    size_t need = ((size_t)MAXP * CD + CD + DIM) * sizeof(float);
    if (ws_size < need) {
        size_t avail = ws_size / sizeof(float);
        size_t fixed = (size_t)CD + DIM;
        P = (avail > fixed + CD) ? (int)((avail - fixed) / CD) : 1;
        if (P > MAXP) P = MAXP;
        if (P < 1) P = 1;
    }

    float* partials = ws;
    float* C = ws + C_OFF;
    float* S = ws + S_OFF;

    ntx_partials<<<P, 256, 0, stream>>>(z, labels, partials, S, out, P);
    ntx_reduce<<<(CD + 255) / 256, 256, 0, stream>>>(partials, C, S, P);
    ntx_loss<<<256, 256, 0, stream>>>(z, labels, C, S, out);
}

// Round 4
// 32.570 us; speedup vs baseline: 3.4835x; 2.2876x over previous
//
#include <hip/hip_runtime.h>
#include <math.h>

#define N_ROWS   8192
#define DIM      128
#define NCLASS   100
#define EPS      1e-8f
#define CD       (NCLASS * DIM)     // 12800

// ws layout (floats): C[CD]
// S is derived per-block in K3's LDS; out lives in d_out.

// K1: zero C and out.
__global__ void __launch_bounds__(256)
ntx_zero(float* __restrict__ C, float* __restrict__ out) {
    int i = blockIdx.x * 256 + threadIdx.x;
    if (i < CD) C[i] = 0.0f;
    if (i == 0) out[0] = 0.0f;
}

// K2: class sums of normalized rows via HW fp atomics (global_atomic_add_f32).
__global__ void __launch_bounds__(256)
ntx_class_sums(const float* __restrict__ z,
               const int*   __restrict__ labels,
               float* __restrict__ C) {
    const int lane  = threadIdx.x & 63;
    const int wave  = (blockIdx.x * 256 + threadIdx.x) >> 6;   // 0..1023
    const int nwave = gridDim.x * 4;

    for (int row = wave; row < N_ROWS; row += nwave) {
        float2 v = ((const float2*)(z + (size_t)row * DIM))[lane];
        float ss = v.x * v.x + v.y * v.y;
        #pragma unroll
        for (int off = 1; off < 64; off <<= 1) ss += __shfl_xor(ss, off);
        float inv = 1.0f / fmaxf(sqrtf(ss), EPS);
        int lbl = labels[row];
        float* dst = C + (size_t)lbl * DIM + 2 * lane;
        unsafeAtomicAdd(dst,     v.x * inv);   // HW global_atomic_add_f32
        unsafeAtomicAdd(dst + 1, v.y * inv);
    }
}

// K3: per-block S from C (LDS), then per-row loss; one atomic per block to out.
__global__ void __launch_bounds__(256)
ntx_loss(const float* __restrict__ z,
         const int*   __restrict__ labels,
         const float* __restrict__ C,
         float* __restrict__ out) {
    __shared__ float Sp[2 * DIM];
    __shared__ float wacc[4];

    // S[d] = sum_c C[c][d], split across two thread-halves.
    {
        int d = threadIdx.x & (DIM - 1);
        int h = threadIdx.x >> 7;                 // 0 or 1
        float s = 0.0f;
        int c0 = h * 50, c1 = c0 + 50;
        for (int c = c0; c < c1; ++c) s += C[c * DIM + d];
        Sp[h * DIM + d] = s;
    }
    __syncthreads();
    if (threadIdx.x < DIM) Sp[threadIdx.x] += Sp[DIM + threadIdx.x];
    __syncthreads();

    const int lane  = threadIdx.x & 63;
    const int wid   = threadIdx.x >> 6;           // wave in block, 0..3
    const int wave  = (blockIdx.x * 256 + threadIdx.x) >> 6;
    const int nwave = gridDim.x * 4;

    float2 s2 = ((const float2*)Sp)[lane];        // S[2*lane], S[2*lane+1]

    float lacc = 0.0f;
    for (int row = wave; row < N_ROWS; row += nwave) {
        float2 v  = ((const float2*)(z + (size_t)row * DIM))[lane];
        int lbl   = labels[row];
        float2 c2 = ((const float2*)(C + (size_t)lbl * DIM))[lane];

        float ss = v.x * v.x + v.y * v.y;
        float dc = v.x * c2.x + v.y * c2.y;
        float dt = v.x * s2.x + v.y * s2.y;
        #pragma unroll
        for (int off = 1; off < 64; off <<= 1) {
            ss += __shfl_xor(ss, off);
            dc += __shfl_xor(dc, off);
            dt += __shfl_xor(dt, off);
        }
        float inv  = 1.0f / fmaxf(sqrtf(ss), EPS);
        float self = ss * inv * inv;              // zn_i . zn_i (diagonal)
        float pos  = dc * inv - self;             // 1/TEMP cancels in pos/tot
        float tot  = dt * inv;
        lacc += -logf(pos / tot);
    }

    if (lane == 0) wacc[wid] = lacc;
    __syncthreads();
    if (threadIdx.x == 0) {
        float b = wacc[0] + wacc[1] + wacc[2] + wacc[3];
        atomicAdd(out, b * (1.0f / (float)N_ROWS));   // 256 contenders, fine
    }
}

extern "C" void kernel_launch(void* const* d_in, const int* in_sizes, int n_in,
                              void* d_out, int out_size, void* d_ws, size_t ws_size,
                              hipStream_t stream) {
    const float* z      = (const float*)d_in[0];
    const int*   labels = (const int*)d_in[1];
    float* out = (float*)d_out;
    float* C   = (float*)d_ws;

    (void)in_sizes; (void)n_in; (void)out_size; (void)ws_size;

    ntx_zero      <<<(CD + 255) / 256, 256, 0, stream>>>(C, out);
    ntx_class_sums<<<256,              256, 0, stream>>>(z, labels, C);
    ntx_loss      <<<256,              256, 0, stream>>>(z, labels, C, out);
}